// Round 15
// baseline (113.114 us; speedup 1.0000x reference)
//
#include <hip/hip_runtime.h>

#define R_MAX 32
#define DIM_OUT 128
#define N_R 66              // 2*R_MAX + 2
#define DIM_IN 139          // 2*N_R + 1 + N_S

typedef float f32x4 __attribute__((ext_vector_type(4)));

// out[bi, i, j, d] = W[d, N_R + clip(i-j+32,0,64)] + (W[d,32] + W[d,132] + W[d,138])
// R14 lesson: plain stores > nt (102.4 vs 105.8); residual vs fill-rate ~23us.
// R15: exact fillBuffer dispatch shape — single grid-stride sweep so all
// resident waves write ONE contiguous ~8MB window moving linearly through the
// buffer (max DRAM row locality), instead of 2048 scattered 4KB fronts.
// Index math is incremental: advance per iter is G/32 j-rows; lane-in-row and
// (at seq=1024) j are per-thread constants, only i steps (+di with carry).
__global__ __launch_bounds__(256) void rpe_kernel(const int* __restrict__ p_seq,
                                                  const float* __restrict__ W,
                                                  f32x4* __restrict__ out,
                                                  unsigned long long n_vec) {
    const unsigned seq = (unsigned)*p_seq;
    const unsigned tid = threadIdx.x;
    const unsigned lane = tid & 31;          // lane-in-row (G % 32 == 0 keeps it fixed)
    const float* w0 = W + (size_t)(lane * 4) * DIM_IN;

    // Per-thread constants (exact reference association order).
    float cst[4];
    f32x4 vhi, vlo;
    #pragma unroll
    for (int k = 0; k < 4; ++k) {
        const float* w = w0 + (size_t)k * DIM_IN;
        cst[k] = (w[R_MAX] + w[2 * N_R]) + w[DIM_IN - 1];
        vhi[k] = w[N_R + 2 * R_MAX] + cst[k];   // bucket 64 (j <= i-32)
        vlo[k] = w[N_R + 0] + cst[k];           // bucket 0  (j >= i+32)
    }

    const unsigned G = gridDim.x * 256u;         // f32x4 units per sweep step
    unsigned long long v = (unsigned long long)blockIdx.x * 256u + tid;

    // Initial (i, j) and per-iteration increments (divide once, then add/carry).
    const unsigned djf = G >> 5;                 // j-rows advanced per iter
    const unsigned jf0 = (unsigned)(v >> 5);
    unsigned j = jf0 % seq;
    unsigned i = (jf0 / seq) % seq;
    const unsigned dj = djf % seq;
    const unsigned di = (djf / seq) % seq;

    for (; v < n_vec; v += G) {
        int b = (int)i - (int)j + R_MAX;
        b = b < 0 ? 0 : (b > 2 * R_MAX ? 2 * R_MAX : b);

        f32x4 val;
        if (b == 0) {
            val = vlo;
        } else if (b == 2 * R_MAX) {
            val = vhi;
        } else {                                  // 65-wide band (~6% of waves)
            val[0] = w0[0 * DIM_IN + N_R + b] + cst[0];
            val[1] = w0[1 * DIM_IN + N_R + b] + cst[1];
            val[2] = w0[2 * DIM_IN + N_R + b] + cst[2];
            val[3] = w0[3 * DIM_IN + N_R + b] + cst[3];
        }
        out[v] = val;

        // advance (i, j) by djf j-rows
        j += dj;
        unsigned c = (j >= seq) ? 1u : 0u;
        j -= c ? seq : 0u;
        i += di + c;
        if (i >= seq) i -= seq;                   // batch wrap is harmless (i resets)
    }
}

extern "C" void kernel_launch(void* const* d_in, const int* in_sizes, int n_in,
                              void* d_out, int out_size, void* d_ws, size_t ws_size,
                              hipStream_t stream) {
    // Inputs per setup_inputs() order: batch_size (int), seq_len (int), W (float32)
    const int* p_seq = (const int*)d_in[1];
    const float* W = (const float*)d_in[2];
    f32x4* out = (f32x4*)d_out;

    const unsigned long long n_vec = (unsigned long long)out_size / 4; // f32x4 units

    // 2048 blocks, grid-stride: one contiguous 8MB window sweeping the buffer
    // (fillBufferAligned's access shape), plain dwordx4 stores.
    rpe_kernel<<<2048, 256, 0, stream>>>(p_seq, W, out, n_vec);
}

// Round 16
// 102.243 us; speedup vs baseline: 1.1063x; 1.1063x over previous
//
#include <hip/hip_runtime.h>

#define R_MAX 32
#define DIM_OUT 128
#define N_R 66              // 2*R_MAX + 2
#define DIM_IN 139          // 2*N_R + 1 + N_S

typedef float f32x4 __attribute__((ext_vector_type(4)));

// out[bi, i, j, d] = W[d, N_R + clip(i-j+32,0,64)] + (W[d,32] + W[d,132] + W[d,138])
// BEST VERIFIED (R14, 102.4us = 5.24 TB/s): 2048 blocks x 256KB contiguous
// chunks, plain dwordx4 stores, ~94% of stores from two per-thread constant
// f32x4 registers, 65-wide diagonal band from L1/L2-resident W gather.
// Tested & refuted for the residual vs 6.8TB/s fills: band source (R12),
// stream count (R13), nt flag (R14: plain wins ~3%), sweep-front (R15: worse).
// Residual = fixed launch/ramp costs at 512MiB + band gather.
__global__ __launch_bounds__(256) void rpe_kernel(const int* __restrict__ p_seq,
                                                  const float* __restrict__ W,
                                                  f32x4* __restrict__ out,
                                                  unsigned long long n_rows) {
    const unsigned seq = (unsigned)*p_seq;
    const unsigned tid = threadIdx.x;
    const unsigned lane = tid & 31;          // column group: floats [lane*4, lane*4+4)
    const float* w0 = W + (size_t)(lane * 4) * DIM_IN;

    // Per-thread constants (exact reference association order).
    float cst[4];
    f32x4 vhi, vlo;
    #pragma unroll
    for (int k = 0; k < 4; ++k) {
        const float* w = w0 + (size_t)k * DIM_IN;
        cst[k] = (w[R_MAX] + w[2 * N_R]) + w[DIM_IN - 1];
        vhi[k] = w[N_R + 2 * R_MAX] + cst[k];   // bucket 64 (j <= i-32)
        vlo[k] = w[N_R + 0] + cst[k];           // bucket 0  (j >= i+32)
    }

    const unsigned n_irows = (unsigned)(n_rows / seq);  // batch * seq
    const unsigned CPR = 2;                              // chunks per i-row
    const unsigned total_chunks = n_irows * CPR;

    for (unsigned chunk = blockIdx.x; chunk < total_chunks; chunk += gridDim.x) {
        const unsigned irow = chunk / CPR;
        const unsigned half = chunk - irow * CPR;
        const int i = (int)(irow % seq);
        const int j0 = (int)((half * seq) / CPR);
        const int j1 = (int)(((half + 1) * seq) / CPR);

        // j < i-31 -> vhi; j in [i-31, i+31] -> band; j >= i+32 -> vlo
        int e1 = i - 31; e1 = e1 < j0 ? j0 : (e1 > j1 ? j1 : e1);
        int e2 = i + 32; e2 = e2 < j0 ? j0 : (e2 > j1 ? j1 : e2);

        f32x4* __restrict__ base = out + (size_t)irow * seq * (DIM_OUT / 4);

        // region 1: pure store stream of vhi
        for (int f = j0 * 32 + (int)tid; f < e1 * 32; f += 256)
            base[f] = vhi;

        // region 2: 65-wide band, direct W gather (L1/L2-resident)
        for (int f = e1 * 32 + (int)tid; f < e2 * 32; f += 256) {
            const int j = f >> 5;
            const int b = i - j + R_MAX;            // in [1, 63]
            f32x4 v;
            v[0] = w0[0 * DIM_IN + N_R + b] + cst[0];
            v[1] = w0[1 * DIM_IN + N_R + b] + cst[1];
            v[2] = w0[2 * DIM_IN + N_R + b] + cst[2];
            v[3] = w0[3 * DIM_IN + N_R + b] + cst[3];
            base[f] = v;
        }

        // region 3: pure store stream of vlo
        for (int f = e2 * 32 + (int)tid; f < j1 * 32; f += 256)
            base[f] = vlo;
    }
}

extern "C" void kernel_launch(void* const* d_in, const int* in_sizes, int n_in,
                              void* d_out, int out_size, void* d_ws, size_t ws_size,
                              hipStream_t stream) {
    // Inputs per setup_inputs() order: batch_size (int), seq_len (int), W (float32)
    const int* p_seq = (const int*)d_in[1];
    const float* W = (const float*)d_in[2];
    f32x4* out = (f32x4*)d_out;

    const unsigned long long n_rows = (unsigned long long)out_size / DIM_OUT;

    // 2048 blocks: for seq=1024, one 256 KB chunk per block (R14 best shape).
    rpe_kernel<<<2048, 256, 0, stream>>>(p_seq, W, out, n_rows);
}